// Round 7
// baseline (605.090 us; speedup 1.0000x reference)
//
#include <hip/hip_runtime.h>
#include <hip/hip_bf16.h>

// SNN "SynapticChain": B=4, T=24, N=4096, F=32, L=3 (+1 final synaptic layer).
// Wave64 = 2 rows (32 lanes/row, lane l = feature index). T-loop in kernel.
// Chain/lin matmuls: binary spikes -> per-block 4-bit LUT in LDS.
// MLP: DPP row_ror systolic (VALU pipe) + ds_swizzle xor16 cross-half merge.
// R7: (1) MLP weights bf16-packed in 64 VGPRs (R5/R6 declared 128 f32 ->
//     compiler rematerialized ~128 L1 loads/wave-t = VMEM-bound ~160us).
//     bf16 is safe: MLP path has NO feedback into spikes. (2) 1024-thread
//     blocks: 16 waves share one 64KB LUT -> >=16 waves/CU (was ~6.4).

namespace {
constexpr int kB = 4;
constexpr int kT = 24;
constexpr int kN = 4096;
constexpr int kF = 32;
constexpr int kNF = kN * kF;

template<int S>
__device__ __forceinline__ float ror16(float x) {
    static_assert(S >= 1 && S <= 15, "row_ror range");
    return __int_as_float(__builtin_amdgcn_update_dpp(
        0, __float_as_int(x), 0x120 | S, 0xF, 0xF, true));
}

__device__ __forceinline__ float swz_x16(float x) {
    // ds_swizzle bitmode: and=0x1F, or=0, xor=0x10 -> lane ^ 16
    return __int_as_float(__builtin_amdgcn_ds_swizzle(__float_as_int(x), 0x401F));
}

__device__ __forceinline__ unsigned pack_bf16(float lo, float hi) {
    unsigned a = (unsigned)__bfloat16_as_ushort(__float2bfloat16(lo));
    unsigned b = (unsigned)__bfloat16_as_ushort(__float2bfloat16(hi));
    return a | (b << 16);
}

template<int S>
__device__ __forceinline__ float upk(const unsigned* wp) {
    const unsigned r = wp[S >> 1];
    if constexpr (S & 1) return __int_as_float(r & 0xffff0000u);
    else                 return __int_as_float(r << 16);
}

// MLP1: rotate t; 4 accumulators (own h1[l], own h1[l+32], partner's pair)
template<int S>
__device__ __forceinline__ void mlp1_steps(float tv,
        const unsigned* w_oa, const unsigned* w_ob,
        const unsigned* w_xa, const unsigned* w_xb,
        float& oa, float& ob, float& xa, float& xb) {
    if constexpr (S <= 15) {
        float v;
        if constexpr (S == 0) v = tv; else v = ror16<S>(tv);
        oa = fmaf(v, upk<S>(w_oa), oa);
        ob = fmaf(v, upk<S>(w_ob), ob);
        xa = fmaf(v, upk<S>(w_xa), xa);
        xb = fmaf(v, upk<S>(w_xb), xb);
        mlp1_steps<S + 1>(tv, w_oa, w_ob, w_xa, w_xb, oa, ob, xa, xb);
    }
}

// MLP2: rotate (g1,g2); 2 accumulators (own out[l], partner out[l^16])
template<int S>
__device__ __forceinline__ void mlp2_steps(float u0, float u1,
        const unsigned* w_o0, const unsigned* w_o1,
        const unsigned* w_x0, const unsigned* w_x1,
        float& oo, float& xx) {
    if constexpr (S <= 15) {
        float v0, v1;
        if constexpr (S == 0) { v0 = u0; v1 = u1; }
        else { v0 = ror16<S>(u0); v1 = ror16<S>(u1); }
        oo = fmaf(v0, upk<S>(w_o0), oo);
        oo = fmaf(v1, upk<S>(w_o1), oo);
        xx = fmaf(v0, upk<S>(w_x0), xx);
        xx = fmaf(v1, upk<S>(w_x1), xx);
        mlp2_steps<S + 1>(u0, u1, w_o0, w_o1, w_x0, w_x1, oo, xx);
    }
}

__global__ __launch_bounds__(1024, 4)
void snn_fused(const float* __restrict__ x,
               const float* __restrict__ alphas,
               const float* __restrict__ betas,
               const float* __restrict__ thrs,
               const float* __restrict__ chain_W,
               const float* __restrict__ chain_b,
               const float* __restrict__ lin_W,
               const float* __restrict__ lin_b,
               const float* __restrict__ W1,
               const float* __restrict__ b1,
               const float* __restrict__ prelu_a,
               const float* __restrict__ W2,
               const float* __restrict__ b2,
               float* __restrict__ out)
{
    const int tid  = threadIdx.x;
    const int lane = tid & 63;
    const int half = lane >> 5;        // row within the wave
    const int l    = lane & 31;        // feature / output index within row
    const int l16  = lane & 15;        // index within DPP 16-row
    const int gbase= l & 16;           // which 16-group of the 32 (0 or 16)
    const int wid  = tid >> 6;         // wave id in block (0..15)
    const int row  = blockIdx.x * 32 + wid * 2 + half;  // 0..16383
    const int b    = row >> 12;
    const int n    = row & (kN - 1);

    // ---- LDS: nibble LUT only (64 KB)
    __shared__ float lut[4][8][16][32];   // [mat][group][nib][j]

    // ---- LUT init: 1024 (mat,g,j) combos, 1 per thread; 16 nibble sums each
    {
        const int idx = tid;
        const int mat = idx >> 8;          // 0..3
        const int g   = (idx >> 5) & 7;    // 0..7
        const int jj  = idx & 31;          // 0..31
        const float* wsrc = (mat < 3) ? (chain_W + ((mat * kF + jj) * kF + g * 4))
                                      : (lin_W + (jj * kF + g * 4));
        const float4 w = *reinterpret_cast<const float4*>(wsrc);
        const float bias = (g == 0) ? ((mat < 3) ? chain_b[mat * kF + jj] : lin_b[jj])
                                    : 0.0f;
        float s[16];
        s[0]  = 0.0f;
        s[1]  = w.x;         s[2]  = w.y;         s[3]  = w.x + w.y;
        s[4]  = w.z;         s[5]  = w.x + w.z;   s[6]  = w.y + w.z;
        s[7]  = s[3] + w.z;  s[8]  = w.w;         s[9]  = w.x + w.w;
        s[10] = w.y + w.w;   s[11] = s[3] + w.w;  s[12] = w.z + w.w;
        s[13] = s[5] + w.w;  s[14] = s[6] + w.w;  s[15] = s[7] + w.w;
#pragma unroll
        for (int nb = 0; nb < 16; ++nb) lut[mat][g][nb][jj] = s[nb] + bias;
    }
    __syncthreads();

    // ---- uniform scalars
    float al[4], be[4], th[4];
#pragma unroll
    for (int i = 0; i < 4; ++i) {
        al[i] = fminf(fmaxf(alphas[i], 0.0f), 1.0f);
        be[i] = fminf(fmaxf(betas[i],  0.0f), 1.0f);
        th[i] = thrs[i];
    }
    const float pa = prelu_a[0];

    // ---- DPP row_ror direction probe: absorb direction into weight order
    const int pr = __builtin_amdgcn_update_dpp(0, lane, 0x121, 0xF, 0xF, true);
    const int d  = (__builtin_amdgcn_readfirstlane(pr) == 1) ? 1 : 15;

    // ---- MLP weights, bf16-packed in rotation order (s=2q low, s=2q+1 high)
    const int lx = l ^ 16;
    unsigned u1_oa[8], u1_ob[8], u1_xa[8], u1_xb[8];
    unsigned u2_o0[8], u2_o1[8], u2_x0[8], u2_x1[8];
#pragma unroll
    for (int q = 0; q < 8; ++q) {
        const int s0 = 2 * q, s1 = 2 * q + 1;
        const int i0 = ((l16 + d * s0) & 15) | gbase;
        const int i1 = ((l16 + d * s1) & 15) | gbase;
        u1_oa[q] = pack_bf16(W1[l         * kF + i0], W1[l         * kF + i1]);
        u1_ob[q] = pack_bf16(W1[(l + 32)  * kF + i0], W1[(l + 32)  * kF + i1]);
        u1_xa[q] = pack_bf16(W1[lx        * kF + i0], W1[lx        * kF + i1]);
        u1_xb[q] = pack_bf16(W1[(lx + 32) * kF + i0], W1[(lx + 32) * kF + i1]);
        u2_o0[q] = pack_bf16(W2[l  * 64 + i0],      W2[l  * 64 + i1]);
        u2_o1[q] = pack_bf16(W2[l  * 64 + i0 + 32], W2[l  * 64 + i1 + 32]);
        u2_x0[q] = pack_bf16(W2[lx * 64 + i0],      W2[lx * 64 + i1]);
        u2_x1[q] = pack_bf16(W2[lx * 64 + i0 + 32], W2[lx * 64 + i1 + 32]);
    }
    const float b1a = b1[l];
    const float b1b = b1[l + 32];
    const float ob  = b2[l];

    float syn[4] = {0.f, 0.f, 0.f, 0.f};
    float mem[4] = {0.f, 0.f, 0.f, 0.f};

    const float* xp = x   + (b * kT * kN + n) * kF + l;
    float*       op = out + (b * kT * kN + n) * kF + l;

    float xv = xp[0];                      // prefetched x for current t

    for (int t = 0; t < kT; ++t) {
        float xnext = 0.0f;
        if (t + 1 < kT) xnext = xp[(t + 1) * kNF];

        float h = xv;
        float transformed = 0.0f;

#pragma unroll
        for (int i = 0; i < 4; ++i) {
            // synaptic_step (reset from PREVIOUS mem, detached)
            const float mo    = mem[i];
            const float reset = ((mo - th[i]) > 0.0f) ? 1.0f : 0.0f;
            syn[i] = al[i] * syn[i] + h;
            mem[i] = be[i] * mem[i] + syn[i] - reset * th[i];
            const bool sp = (mem[i] - th[i]) > 0.0f;

            const unsigned long long m64 = __ballot(sp);
            const unsigned m32 = half ? (unsigned)(m64 >> 32) : (unsigned)m64;

            // binary matmul via nibble LUT (bias folded into g=0)
            float v[8];
#pragma unroll
            for (int g = 0; g < 8; ++g) {
                const unsigned nib = (m32 >> (4 * g)) & 15u;
                v[g] = lut[i][g][nib][l];
            }
            const float acc = ((v[0] + v[1]) + (v[2] + v[3]))
                            + ((v[4] + v[5]) + (v[6] + v[7]));
            if (i < 3) h = acc; else transformed = acc;
        }

        // ---- MLP1: 32 -> 64 via DPP systolic (no LDS, weights in regs)
        float oa = b1a, obv = b1b, xa = 0.0f, xb = 0.0f;
        mlp1_steps<0>(transformed, u1_oa, u1_ob, u1_xa, u1_xb, oa, obv, xa, xb);
        const float h1a = oa  + swz_x16(xa);
        const float h1b = obv + swz_x16(xb);
        const float g1 = (h1a > 0.0f) ? h1a : pa * h1a;
        const float g2 = (h1b > 0.0f) ? h1b : pa * h1b;

        // ---- MLP2: 64 -> 32 via DPP systolic
        float oo = ob, xx = 0.0f;
        mlp2_steps<0>(g1, g2, u2_o0, u2_o1, u2_x0, u2_x1, oo, xx);
        op[t * kNF] = oo + swz_x16(xx);

        xv = xnext;
    }
}
} // namespace

extern "C" void kernel_launch(void* const* d_in, const int* in_sizes, int n_in,
                              void* d_out, int out_size, void* d_ws, size_t ws_size,
                              hipStream_t stream) {
    const float* x        = (const float*)d_in[0];
    const float* alphas   = (const float*)d_in[1];
    const float* betas    = (const float*)d_in[2];
    const float* thrs     = (const float*)d_in[3];
    const float* chain_W  = (const float*)d_in[4];
    const float* chain_b  = (const float*)d_in[5];
    const float* lin_W    = (const float*)d_in[6];
    const float* lin_b    = (const float*)d_in[7];
    const float* W1       = (const float*)d_in[8];
    const float* b1       = (const float*)d_in[9];
    const float* prelu_a  = (const float*)d_in[10];
    const float* W2       = (const float*)d_in[11];
    const float* b2       = (const float*)d_in[12];
    float* out            = (float*)d_out;

    const int rows   = kB * kN;          // 16384
    const int blocks = rows / 32;        // 512 blocks * 16 waves * 2 rows/wave
    hipLaunchKernelGGL(snn_fused, dim3(blocks), dim3(1024), 0, stream,
                       x, alphas, betas, thrs, chain_W, chain_b, lin_W, lin_b,
                       W1, b1, prelu_a, W2, b2, out);
}

// Round 8
// 604.515 us; speedup vs baseline: 1.0010x; 1.0010x over previous
//
#include <hip/hip_runtime.h>
#include <hip/hip_bf16.h>

// SNN "SynapticChain": B=4, T=24, N=4096, F=32, L=3 (+1 final synaptic layer).
// Wave64 = 2 rows (32 lanes/row, lane l = feature index). T-loop in kernel.
// Chain/lin matmuls: binary spikes -> per-block 4-bit LUT in LDS.
// MLP: DPP row_ror systolic (VALU pipe) + ds_swizzle xor16 cross-half merge;
//      weights bf16-packed in 64 VGPRs (no LDS, no remat loads).
// R8: __launch_bounds__(1024,1). Empirically (R4/R5/R7) the 2nd arg acts as
//     CUDA-style min-BLOCKS/CU (clamped to 32 waves/CU): (512,4)&(1024,4)->64
//     VGPR cap (spill), (512,2)->128 cap. (1024,1) = 16 waves/CU = 4/SIMD ->
//     128 cap, which the bf16-packed weight set (~110-125 VGPR) fits.

namespace {
constexpr int kB = 4;
constexpr int kT = 24;
constexpr int kN = 4096;
constexpr int kF = 32;
constexpr int kNF = kN * kF;

template<int S>
__device__ __forceinline__ float ror16(float x) {
    static_assert(S >= 1 && S <= 15, "row_ror range");
    return __int_as_float(__builtin_amdgcn_update_dpp(
        0, __float_as_int(x), 0x120 | S, 0xF, 0xF, true));
}

__device__ __forceinline__ float swz_x16(float x) {
    // ds_swizzle bitmode: and=0x1F, or=0, xor=0x10 -> lane ^ 16
    return __int_as_float(__builtin_amdgcn_ds_swizzle(__float_as_int(x), 0x401F));
}

__device__ __forceinline__ unsigned pack_bf16(float lo, float hi) {
    unsigned a = (unsigned)__bfloat16_as_ushort(__float2bfloat16(lo));
    unsigned b = (unsigned)__bfloat16_as_ushort(__float2bfloat16(hi));
    return a | (b << 16);
}

template<int S>
__device__ __forceinline__ float upk(const unsigned* wp) {
    const unsigned r = wp[S >> 1];
    if constexpr (S & 1) return __int_as_float(r & 0xffff0000u);
    else                 return __int_as_float(r << 16);
}

// MLP1: rotate t; 4 accumulators (own h1[l], own h1[l+32], partner's pair)
template<int S>
__device__ __forceinline__ void mlp1_steps(float tv,
        const unsigned* w_oa, const unsigned* w_ob,
        const unsigned* w_xa, const unsigned* w_xb,
        float& oa, float& ob, float& xa, float& xb) {
    if constexpr (S <= 15) {
        float v;
        if constexpr (S == 0) v = tv; else v = ror16<S>(tv);
        oa = fmaf(v, upk<S>(w_oa), oa);
        ob = fmaf(v, upk<S>(w_ob), ob);
        xa = fmaf(v, upk<S>(w_xa), xa);
        xb = fmaf(v, upk<S>(w_xb), xb);
        mlp1_steps<S + 1>(tv, w_oa, w_ob, w_xa, w_xb, oa, ob, xa, xb);
    }
}

// MLP2: rotate (g1,g2); 2 accumulators (own out[l], partner out[l^16])
template<int S>
__device__ __forceinline__ void mlp2_steps(float u0, float u1,
        const unsigned* w_o0, const unsigned* w_o1,
        const unsigned* w_x0, const unsigned* w_x1,
        float& oo, float& xx) {
    if constexpr (S <= 15) {
        float v0, v1;
        if constexpr (S == 0) { v0 = u0; v1 = u1; }
        else { v0 = ror16<S>(u0); v1 = ror16<S>(u1); }
        oo = fmaf(v0, upk<S>(w_o0), oo);
        oo = fmaf(v1, upk<S>(w_o1), oo);
        xx = fmaf(v0, upk<S>(w_x0), xx);
        xx = fmaf(v1, upk<S>(w_x1), xx);
        mlp2_steps<S + 1>(u0, u1, w_o0, w_o1, w_x0, w_x1, oo, xx);
    }
}

__global__ __launch_bounds__(1024, 1)
void snn_fused(const float* __restrict__ x,
               const float* __restrict__ alphas,
               const float* __restrict__ betas,
               const float* __restrict__ thrs,
               const float* __restrict__ chain_W,
               const float* __restrict__ chain_b,
               const float* __restrict__ lin_W,
               const float* __restrict__ lin_b,
               const float* __restrict__ W1,
               const float* __restrict__ b1,
               const float* __restrict__ prelu_a,
               const float* __restrict__ W2,
               const float* __restrict__ b2,
               float* __restrict__ out)
{
    const int tid  = threadIdx.x;
    const int lane = tid & 63;
    const int half = lane >> 5;        // row within the wave
    const int l    = lane & 31;        // feature / output index within row
    const int l16  = lane & 15;        // index within DPP 16-row
    const int gbase= l & 16;           // which 16-group of the 32 (0 or 16)
    const int wid  = tid >> 6;         // wave id in block (0..15)
    const int row  = blockIdx.x * 32 + wid * 2 + half;  // 0..16383
    const int b    = row >> 12;
    const int n    = row & (kN - 1);

    // ---- LDS: nibble LUT only (64 KB)
    __shared__ float lut[4][8][16][32];   // [mat][group][nib][j]

    // ---- LUT init: 1024 (mat,g,j) combos, 1 per thread; 16 nibble sums each
    {
        const int idx = tid;
        const int mat = idx >> 8;          // 0..3
        const int g   = (idx >> 5) & 7;    // 0..7
        const int jj  = idx & 31;          // 0..31
        const float* wsrc = (mat < 3) ? (chain_W + ((mat * kF + jj) * kF + g * 4))
                                      : (lin_W + (jj * kF + g * 4));
        const float4 w = *reinterpret_cast<const float4*>(wsrc);
        const float bias = (g == 0) ? ((mat < 3) ? chain_b[mat * kF + jj] : lin_b[jj])
                                    : 0.0f;
        float s[16];
        s[0]  = 0.0f;
        s[1]  = w.x;         s[2]  = w.y;         s[3]  = w.x + w.y;
        s[4]  = w.z;         s[5]  = w.x + w.z;   s[6]  = w.y + w.z;
        s[7]  = s[3] + w.z;  s[8]  = w.w;         s[9]  = w.x + w.w;
        s[10] = w.y + w.w;   s[11] = s[3] + w.w;  s[12] = w.z + w.w;
        s[13] = s[5] + w.w;  s[14] = s[6] + w.w;  s[15] = s[7] + w.w;
#pragma unroll
        for (int nb = 0; nb < 16; ++nb) lut[mat][g][nb][jj] = s[nb] + bias;
    }
    __syncthreads();

    // ---- uniform scalars
    float al[4], be[4], th[4];
#pragma unroll
    for (int i = 0; i < 4; ++i) {
        al[i] = fminf(fmaxf(alphas[i], 0.0f), 1.0f);
        be[i] = fminf(fmaxf(betas[i],  0.0f), 1.0f);
        th[i] = thrs[i];
    }
    const float pa = prelu_a[0];

    // ---- DPP row_ror direction probe: absorb direction into weight order
    const int pr = __builtin_amdgcn_update_dpp(0, lane, 0x121, 0xF, 0xF, true);
    const int d  = (__builtin_amdgcn_readfirstlane(pr) == 1) ? 1 : 15;

    // ---- MLP weights, bf16-packed in rotation order (s=2q low, s=2q+1 high)
    const int lx = l ^ 16;
    unsigned u1_oa[8], u1_ob[8], u1_xa[8], u1_xb[8];
    unsigned u2_o0[8], u2_o1[8], u2_x0[8], u2_x1[8];
#pragma unroll
    for (int q = 0; q < 8; ++q) {
        const int s0 = 2 * q, s1 = 2 * q + 1;
        const int i0 = ((l16 + d * s0) & 15) | gbase;
        const int i1 = ((l16 + d * s1) & 15) | gbase;
        u1_oa[q] = pack_bf16(W1[l         * kF + i0], W1[l         * kF + i1]);
        u1_ob[q] = pack_bf16(W1[(l + 32)  * kF + i0], W1[(l + 32)  * kF + i1]);
        u1_xa[q] = pack_bf16(W1[lx        * kF + i0], W1[lx        * kF + i1]);
        u1_xb[q] = pack_bf16(W1[(lx + 32) * kF + i0], W1[(lx + 32) * kF + i1]);
        u2_o0[q] = pack_bf16(W2[l  * 64 + i0],      W2[l  * 64 + i1]);
        u2_o1[q] = pack_bf16(W2[l  * 64 + i0 + 32], W2[l  * 64 + i1 + 32]);
        u2_x0[q] = pack_bf16(W2[lx * 64 + i0],      W2[lx * 64 + i1]);
        u2_x1[q] = pack_bf16(W2[lx * 64 + i0 + 32], W2[lx * 64 + i1 + 32]);
    }
    const float b1a = b1[l];
    const float b1b = b1[l + 32];
    const float ob  = b2[l];

    float syn[4] = {0.f, 0.f, 0.f, 0.f};
    float mem[4] = {0.f, 0.f, 0.f, 0.f};

    const float* xp = x   + (b * kT * kN + n) * kF + l;
    float*       op = out + (b * kT * kN + n) * kF + l;

    float xv = xp[0];                      // prefetched x for current t

    for (int t = 0; t < kT; ++t) {
        float xnext = 0.0f;
        if (t + 1 < kT) xnext = xp[(t + 1) * kNF];

        float h = xv;
        float transformed = 0.0f;

#pragma unroll
        for (int i = 0; i < 4; ++i) {
            // synaptic_step (reset from PREVIOUS mem, detached)
            const float mo    = mem[i];
            const float reset = ((mo - th[i]) > 0.0f) ? 1.0f : 0.0f;
            syn[i] = al[i] * syn[i] + h;
            mem[i] = be[i] * mem[i] + syn[i] - reset * th[i];
            const bool sp = (mem[i] - th[i]) > 0.0f;

            const unsigned long long m64 = __ballot(sp);
            const unsigned m32 = half ? (unsigned)(m64 >> 32) : (unsigned)m64;

            // binary matmul via nibble LUT (bias folded into g=0)
            float v[8];
#pragma unroll
            for (int g = 0; g < 8; ++g) {
                const unsigned nib = (m32 >> (4 * g)) & 15u;
                v[g] = lut[i][g][nib][l];
            }
            const float acc = ((v[0] + v[1]) + (v[2] + v[3]))
                            + ((v[4] + v[5]) + (v[6] + v[7]));
            if (i < 3) h = acc; else transformed = acc;
        }

        // ---- MLP1: 32 -> 64 via DPP systolic (no LDS, weights in regs)
        float oa = b1a, obv = b1b, xa = 0.0f, xb = 0.0f;
        mlp1_steps<0>(transformed, u1_oa, u1_ob, u1_xa, u1_xb, oa, obv, xa, xb);
        const float h1a = oa  + swz_x16(xa);
        const float h1b = obv + swz_x16(xb);
        const float g1 = (h1a > 0.0f) ? h1a : pa * h1a;
        const float g2 = (h1b > 0.0f) ? h1b : pa * h1b;

        // ---- MLP2: 64 -> 32 via DPP systolic
        float oo = ob, xx = 0.0f;
        mlp2_steps<0>(g1, g2, u2_o0, u2_o1, u2_x0, u2_x1, oo, xx);
        op[t * kNF] = oo + swz_x16(xx);

        xv = xnext;
    }
}
} // namespace

extern "C" void kernel_launch(void* const* d_in, const int* in_sizes, int n_in,
                              void* d_out, int out_size, void* d_ws, size_t ws_size,
                              hipStream_t stream) {
    const float* x        = (const float*)d_in[0];
    const float* alphas   = (const float*)d_in[1];
    const float* betas    = (const float*)d_in[2];
    const float* thrs     = (const float*)d_in[3];
    const float* chain_W  = (const float*)d_in[4];
    const float* chain_b  = (const float*)d_in[5];
    const float* lin_W    = (const float*)d_in[6];
    const float* lin_b    = (const float*)d_in[7];
    const float* W1       = (const float*)d_in[8];
    const float* b1       = (const float*)d_in[9];
    const float* prelu_a  = (const float*)d_in[10];
    const float* W2       = (const float*)d_in[11];
    const float* b2       = (const float*)d_in[12];
    float* out            = (float*)d_out;

    const int rows   = kB * kN;          // 16384
    const int blocks = rows / 32;        // 512 blocks * 16 waves * 2 rows/wave
    hipLaunchKernelGGL(snn_fused, dim3(blocks), dim3(1024), 0, stream,
                       x, alphas, betas, thrs, chain_W, chain_b, lin_W, lin_b,
                       W1, b1, prelu_a, W2, b2, out);
}

// Round 9
// 167.242 us; speedup vs baseline: 3.6180x; 3.6146x over previous
//
#include <hip/hip_runtime.h>
#include <hip/hip_bf16.h>

// SNN "SynapticChain": B=4, T=24, N=4096, F=32, L=3 (+1 final synaptic layer).
// Wave64 = 2 rows (32 lanes/row, lane l = feature index). T-loop in kernel.
// Chain/lin matmuls: binary spikes -> per-block 4-bit LUT in LDS.
// MLP: DPP row_ror systolic (VALU pipe) + ds_swizzle xor16 cross-half merge;
//      weights bf16-packed in 64 VGPRs (no LDS, no remat loads).
// R9: back to the EMPIRICALLY proven envelope: 512-thread blocks +
//     __launch_bounds__(512,2) (R5: VGPR=120 no spill). All 1024-thread
//     configs pin VGPR=64 and spill (R7/R8). Math identical to R7/R8.

namespace {
constexpr int kB = 4;
constexpr int kT = 24;
constexpr int kN = 4096;
constexpr int kF = 32;
constexpr int kNF = kN * kF;

template<int S>
__device__ __forceinline__ float ror16(float x) {
    static_assert(S >= 1 && S <= 15, "row_ror range");
    return __int_as_float(__builtin_amdgcn_update_dpp(
        0, __float_as_int(x), 0x120 | S, 0xF, 0xF, true));
}

__device__ __forceinline__ float swz_x16(float x) {
    // ds_swizzle bitmode: and=0x1F, or=0, xor=0x10 -> lane ^ 16
    return __int_as_float(__builtin_amdgcn_ds_swizzle(__float_as_int(x), 0x401F));
}

__device__ __forceinline__ unsigned pack_bf16(float lo, float hi) {
    unsigned a = (unsigned)__bfloat16_as_ushort(__float2bfloat16(lo));
    unsigned b = (unsigned)__bfloat16_as_ushort(__float2bfloat16(hi));
    return a | (b << 16);
}

template<int S>
__device__ __forceinline__ float upk(const unsigned* wp) {
    const unsigned r = wp[S >> 1];
    if constexpr (S & 1) return __int_as_float(r & 0xffff0000u);
    else                 return __int_as_float(r << 16);
}

// MLP1: rotate t; 4 accumulators (own h1[l], own h1[l+32], partner's pair)
template<int S>
__device__ __forceinline__ void mlp1_steps(float tv,
        const unsigned* w_oa, const unsigned* w_ob,
        const unsigned* w_xa, const unsigned* w_xb,
        float& oa, float& ob, float& xa, float& xb) {
    if constexpr (S <= 15) {
        float v;
        if constexpr (S == 0) v = tv; else v = ror16<S>(tv);
        oa = fmaf(v, upk<S>(w_oa), oa);
        ob = fmaf(v, upk<S>(w_ob), ob);
        xa = fmaf(v, upk<S>(w_xa), xa);
        xb = fmaf(v, upk<S>(w_xb), xb);
        mlp1_steps<S + 1>(tv, w_oa, w_ob, w_xa, w_xb, oa, ob, xa, xb);
    }
}

// MLP2: rotate (g1,g2); 2 accumulators (own out[l], partner out[l^16])
template<int S>
__device__ __forceinline__ void mlp2_steps(float u0, float u1,
        const unsigned* w_o0, const unsigned* w_o1,
        const unsigned* w_x0, const unsigned* w_x1,
        float& oo, float& xx) {
    if constexpr (S <= 15) {
        float v0, v1;
        if constexpr (S == 0) { v0 = u0; v1 = u1; }
        else { v0 = ror16<S>(u0); v1 = ror16<S>(u1); }
        oo = fmaf(v0, upk<S>(w_o0), oo);
        oo = fmaf(v1, upk<S>(w_o1), oo);
        xx = fmaf(v0, upk<S>(w_x0), xx);
        xx = fmaf(v1, upk<S>(w_x1), xx);
        mlp2_steps<S + 1>(u0, u1, w_o0, w_o1, w_x0, w_x1, oo, xx);
    }
}

__global__ __launch_bounds__(512, 2)
void snn_fused(const float* __restrict__ x,
               const float* __restrict__ alphas,
               const float* __restrict__ betas,
               const float* __restrict__ thrs,
               const float* __restrict__ chain_W,
               const float* __restrict__ chain_b,
               const float* __restrict__ lin_W,
               const float* __restrict__ lin_b,
               const float* __restrict__ W1,
               const float* __restrict__ b1,
               const float* __restrict__ prelu_a,
               const float* __restrict__ W2,
               const float* __restrict__ b2,
               float* __restrict__ out)
{
    const int tid  = threadIdx.x;
    const int lane = tid & 63;
    const int half = lane >> 5;        // row within the wave
    const int l    = lane & 31;        // feature / output index within row
    const int l16  = lane & 15;        // index within DPP 16-row
    const int gbase= l & 16;           // which 16-group of the 32 (0 or 16)
    const int wid  = tid >> 6;         // wave id in block (0..7)
    const int row  = blockIdx.x * 16 + wid * 2 + half;  // 0..16383
    const int b    = row >> 12;
    const int n    = row & (kN - 1);

    // ---- LDS: nibble LUT only (64 KB)
    __shared__ float lut[4][8][16][32];   // [mat][group][nib][j]

    // ---- LUT init: 1024 (mat,g,j) combos, 2 per thread; 16 nibble sums each
#pragma unroll
    for (int c = 0; c < 2; ++c) {
        const int idx = tid + c * 512;
        const int mat = idx >> 8;          // 0..3
        const int g   = (idx >> 5) & 7;    // 0..7
        const int jj  = idx & 31;          // 0..31
        const float* wsrc = (mat < 3) ? (chain_W + ((mat * kF + jj) * kF + g * 4))
                                      : (lin_W + (jj * kF + g * 4));
        const float4 w = *reinterpret_cast<const float4*>(wsrc);
        const float bias = (g == 0) ? ((mat < 3) ? chain_b[mat * kF + jj] : lin_b[jj])
                                    : 0.0f;
        float s[16];
        s[0]  = 0.0f;
        s[1]  = w.x;         s[2]  = w.y;         s[3]  = w.x + w.y;
        s[4]  = w.z;         s[5]  = w.x + w.z;   s[6]  = w.y + w.z;
        s[7]  = s[3] + w.z;  s[8]  = w.w;         s[9]  = w.x + w.w;
        s[10] = w.y + w.w;   s[11] = s[3] + w.w;  s[12] = w.z + w.w;
        s[13] = s[5] + w.w;  s[14] = s[6] + w.w;  s[15] = s[7] + w.w;
#pragma unroll
        for (int nb = 0; nb < 16; ++nb) lut[mat][g][nb][jj] = s[nb] + bias;
    }
    __syncthreads();

    // ---- uniform scalars
    float al[4], be[4], th[4];
#pragma unroll
    for (int i = 0; i < 4; ++i) {
        al[i] = fminf(fmaxf(alphas[i], 0.0f), 1.0f);
        be[i] = fminf(fmaxf(betas[i],  0.0f), 1.0f);
        th[i] = thrs[i];
    }
    const float pa = prelu_a[0];

    // ---- DPP row_ror direction probe: absorb direction into weight order
    const int pr = __builtin_amdgcn_update_dpp(0, lane, 0x121, 0xF, 0xF, true);
    const int d  = (__builtin_amdgcn_readfirstlane(pr) == 1) ? 1 : 15;

    // ---- MLP weights, bf16-packed in rotation order (s=2q low, s=2q+1 high)
    const int lx = l ^ 16;
    unsigned u1_oa[8], u1_ob[8], u1_xa[8], u1_xb[8];
    unsigned u2_o0[8], u2_o1[8], u2_x0[8], u2_x1[8];
#pragma unroll
    for (int q = 0; q < 8; ++q) {
        const int s0 = 2 * q, s1 = 2 * q + 1;
        const int i0 = ((l16 + d * s0) & 15) | gbase;
        const int i1 = ((l16 + d * s1) & 15) | gbase;
        u1_oa[q] = pack_bf16(W1[l         * kF + i0], W1[l         * kF + i1]);
        u1_ob[q] = pack_bf16(W1[(l + 32)  * kF + i0], W1[(l + 32)  * kF + i1]);
        u1_xa[q] = pack_bf16(W1[lx        * kF + i0], W1[lx        * kF + i1]);
        u1_xb[q] = pack_bf16(W1[(lx + 32) * kF + i0], W1[(lx + 32) * kF + i1]);
        u2_o0[q] = pack_bf16(W2[l  * 64 + i0],      W2[l  * 64 + i1]);
        u2_o1[q] = pack_bf16(W2[l  * 64 + i0 + 32], W2[l  * 64 + i1 + 32]);
        u2_x0[q] = pack_bf16(W2[lx * 64 + i0],      W2[lx * 64 + i1]);
        u2_x1[q] = pack_bf16(W2[lx * 64 + i0 + 32], W2[lx * 64 + i1 + 32]);
    }
    const float b1a = b1[l];
    const float b1b = b1[l + 32];
    const float ob  = b2[l];

    float syn[4] = {0.f, 0.f, 0.f, 0.f};
    float mem[4] = {0.f, 0.f, 0.f, 0.f};

    const float* xp = x   + (b * kT * kN + n) * kF + l;
    float*       op = out + (b * kT * kN + n) * kF + l;

    float xv = xp[0];                      // prefetched x for current t

    for (int t = 0; t < kT; ++t) {
        float xnext = 0.0f;
        if (t + 1 < kT) xnext = xp[(t + 1) * kNF];

        float h = xv;
        float transformed = 0.0f;

#pragma unroll
        for (int i = 0; i < 4; ++i) {
            // synaptic_step (reset from PREVIOUS mem, detached)
            const float mo    = mem[i];
            const float reset = ((mo - th[i]) > 0.0f) ? 1.0f : 0.0f;
            syn[i] = al[i] * syn[i] + h;
            mem[i] = be[i] * mem[i] + syn[i] - reset * th[i];
            const bool sp = (mem[i] - th[i]) > 0.0f;

            const unsigned long long m64 = __ballot(sp);
            const unsigned m32 = half ? (unsigned)(m64 >> 32) : (unsigned)m64;

            // binary matmul via nibble LUT (bias folded into g=0)
            float v[8];
#pragma unroll
            for (int g = 0; g < 8; ++g) {
                const unsigned nib = (m32 >> (4 * g)) & 15u;
                v[g] = lut[i][g][nib][l];
            }
            const float acc = ((v[0] + v[1]) + (v[2] + v[3]))
                            + ((v[4] + v[5]) + (v[6] + v[7]));
            if (i < 3) h = acc; else transformed = acc;
        }

        // ---- MLP1: 32 -> 64 via DPP systolic (no LDS, weights in regs)
        float oa = b1a, obv = b1b, xa = 0.0f, xb = 0.0f;
        mlp1_steps<0>(transformed, u1_oa, u1_ob, u1_xa, u1_xb, oa, obv, xa, xb);
        const float h1a = oa  + swz_x16(xa);
        const float h1b = obv + swz_x16(xb);
        const float g1 = (h1a > 0.0f) ? h1a : pa * h1a;
        const float g2 = (h1b > 0.0f) ? h1b : pa * h1b;

        // ---- MLP2: 64 -> 32 via DPP systolic
        float oo = ob, xx = 0.0f;
        mlp2_steps<0>(g1, g2, u2_o0, u2_o1, u2_x0, u2_x1, oo, xx);
        op[t * kNF] = oo + swz_x16(xx);

        xv = xnext;
    }
}
} // namespace

extern "C" void kernel_launch(void* const* d_in, const int* in_sizes, int n_in,
                              void* d_out, int out_size, void* d_ws, size_t ws_size,
                              hipStream_t stream) {
    const float* x        = (const float*)d_in[0];
    const float* alphas   = (const float*)d_in[1];
    const float* betas    = (const float*)d_in[2];
    const float* thrs     = (const float*)d_in[3];
    const float* chain_W  = (const float*)d_in[4];
    const float* chain_b  = (const float*)d_in[5];
    const float* lin_W    = (const float*)d_in[6];
    const float* lin_b    = (const float*)d_in[7];
    const float* W1       = (const float*)d_in[8];
    const float* b1       = (const float*)d_in[9];
    const float* prelu_a  = (const float*)d_in[10];
    const float* W2       = (const float*)d_in[11];
    const float* b2       = (const float*)d_in[12];
    float* out            = (float*)d_out;

    const int rows   = kB * kN;          // 16384
    const int blocks = rows / 16;        // 1024 blocks * 8 waves * 2 rows/wave
    hipLaunchKernelGGL(snn_fused, dim3(blocks), dim3(512), 0, stream,
                       x, alphas, betas, thrs, chain_W, chain_b, lin_W, lin_b,
                       W1, b1, prelu_a, W2, b2, out);
}

// Round 10
// 132.309 us; speedup vs baseline: 4.5733x; 1.2640x over previous
//
#include <hip/hip_runtime.h>
#include <hip/hip_bf16.h>

// SNN "SynapticChain": B=4, T=24, N=4096, F=32, L=3 (+1 final synaptic layer).
// R10: 2 rows per LANE (4 rows/wave, 512 blocks x 512 threads, (512,2)).
// R3/R5/R6/R9 all ~160us with VALU~54%/LDS both half-idle at ~2 waves/SIMD:
// serial-chain latency-bound. Two in-stream chains/lane interleave to fill
// the bubbles; LUT + bf16-packed MLP weight registers are SHARED across the
// lane's two rows (same l), so weight VGPRs and unpacks don't grow.
// Chain/lin matmuls: binary spikes -> per-block 4-bit LUT in LDS.
// MLP: DPP row_ror systolic + ds_swizzle xor16 cross-half merge.

namespace {
constexpr int kB = 4;
constexpr int kT = 24;
constexpr int kN = 4096;
constexpr int kF = 32;
constexpr int kNF = kN * kF;

template<int S>
__device__ __forceinline__ float ror16(float x) {
    static_assert(S >= 1 && S <= 15, "row_ror range");
    return __int_as_float(__builtin_amdgcn_update_dpp(
        0, __float_as_int(x), 0x120 | S, 0xF, 0xF, true));
}

__device__ __forceinline__ float swz_x16(float x) {
    // ds_swizzle bitmode: and=0x1F, or=0, xor=0x10 -> lane ^ 16
    return __int_as_float(__builtin_amdgcn_ds_swizzle(__float_as_int(x), 0x401F));
}

__device__ __forceinline__ unsigned pack_bf16(float lo, float hi) {
    unsigned a = (unsigned)__bfloat16_as_ushort(__float2bfloat16(lo));
    unsigned b = (unsigned)__bfloat16_as_ushort(__float2bfloat16(hi));
    return a | (b << 16);
}

template<int S>
__device__ __forceinline__ float upk(const unsigned* wp) {
    const unsigned r = wp[S >> 1];
    if constexpr (S & 1) return __int_as_float(r & 0xffff0000u);
    else                 return __int_as_float(r << 16);
}

// MLP1 for two rows: weights unpacked ONCE, FMA'd into both rows' accs.
template<int S>
__device__ __forceinline__ void mlp1_steps2(float tvA, float tvB,
        const unsigned* w_oa, const unsigned* w_ob,
        const unsigned* w_xa, const unsigned* w_xb,
        float& oaA, float& obA, float& xaA, float& xbA,
        float& oaB, float& obB, float& xaB, float& xbB) {
    if constexpr (S <= 15) {
        float vA, vB;
        if constexpr (S == 0) { vA = tvA; vB = tvB; }
        else { vA = ror16<S>(tvA); vB = ror16<S>(tvB); }
        const float w0 = upk<S>(w_oa);
        const float w1 = upk<S>(w_ob);
        const float w2 = upk<S>(w_xa);
        const float w3 = upk<S>(w_xb);
        oaA = fmaf(vA, w0, oaA);  oaB = fmaf(vB, w0, oaB);
        obA = fmaf(vA, w1, obA);  obB = fmaf(vB, w1, obB);
        xaA = fmaf(vA, w2, xaA);  xaB = fmaf(vB, w2, xaB);
        xbA = fmaf(vA, w3, xbA);  xbB = fmaf(vB, w3, xbB);
        mlp1_steps2<S + 1>(tvA, tvB, w_oa, w_ob, w_xa, w_xb,
                           oaA, obA, xaA, xbA, oaB, obB, xaB, xbB);
    }
}

// MLP2 for two rows: 4 shared unpacks, 8 FMAs per step.
template<int S>
__device__ __forceinline__ void mlp2_steps2(
        float u0A, float u1A, float u0B, float u1B,
        const unsigned* w_o0, const unsigned* w_o1,
        const unsigned* w_x0, const unsigned* w_x1,
        float& ooA, float& xxA, float& ooB, float& xxB) {
    if constexpr (S <= 15) {
        float v0A, v1A, v0B, v1B;
        if constexpr (S == 0) { v0A = u0A; v1A = u1A; v0B = u0B; v1B = u1B; }
        else {
            v0A = ror16<S>(u0A); v1A = ror16<S>(u1A);
            v0B = ror16<S>(u0B); v1B = ror16<S>(u1B);
        }
        const float w0 = upk<S>(w_o0);
        const float w1 = upk<S>(w_o1);
        const float w2 = upk<S>(w_x0);
        const float w3 = upk<S>(w_x1);
        ooA = fmaf(v0A, w0, ooA);  ooB = fmaf(v0B, w0, ooB);
        ooA = fmaf(v1A, w1, ooA);  ooB = fmaf(v1B, w1, ooB);
        xxA = fmaf(v0A, w2, xxA);  xxB = fmaf(v0B, w2, xxB);
        xxA = fmaf(v1A, w3, xxA);  xxB = fmaf(v1B, w3, xxB);
        mlp2_steps2<S + 1>(u0A, u1A, u0B, u1B, w_o0, w_o1, w_x0, w_x1,
                           ooA, xxA, ooB, xxB);
    }
}

__global__ __launch_bounds__(512, 2)
void snn_fused(const float* __restrict__ x,
               const float* __restrict__ alphas,
               const float* __restrict__ betas,
               const float* __restrict__ thrs,
               const float* __restrict__ chain_W,
               const float* __restrict__ chain_b,
               const float* __restrict__ lin_W,
               const float* __restrict__ lin_b,
               const float* __restrict__ W1,
               const float* __restrict__ b1,
               const float* __restrict__ prelu_a,
               const float* __restrict__ W2,
               const float* __restrict__ b2,
               float* __restrict__ out)
{
    const int tid  = threadIdx.x;
    const int lane = tid & 63;
    const int half = lane >> 5;        // sub-row within the wave
    const int l    = lane & 31;        // feature / output index within row
    const int l16  = lane & 15;        // index within DPP 16-row
    const int gbase= l & 16;           // which 16-group of the 32 (0 or 16)
    const int wid  = tid >> 6;         // wave id in block (0..7)
    // 4 rows per wave: rowA = base+half, rowB = base+half+2
    const int rowA = blockIdx.x * 32 + wid * 4 + half;
    const int rowB = rowA + 2;
    const int bA   = rowA >> 12;
    const int nA   = rowA & (kN - 1);
    const int bB   = rowB >> 12;
    const int nB   = rowB & (kN - 1);

    // ---- LDS: nibble LUT only (64 KB)
    __shared__ float lut[4][8][16][32];   // [mat][group][nib][j]

    // ---- LUT init: 1024 (mat,g,j) combos, 2 per thread; 16 nibble sums each
#pragma unroll
    for (int c = 0; c < 2; ++c) {
        const int idx = tid + c * 512;
        const int mat = idx >> 8;          // 0..3
        const int g   = (idx >> 5) & 7;    // 0..7
        const int jj  = idx & 31;          // 0..31
        const float* wsrc = (mat < 3) ? (chain_W + ((mat * kF + jj) * kF + g * 4))
                                      : (lin_W + (jj * kF + g * 4));
        const float4 w = *reinterpret_cast<const float4*>(wsrc);
        const float bias = (g == 0) ? ((mat < 3) ? chain_b[mat * kF + jj] : lin_b[jj])
                                    : 0.0f;
        float s[16];
        s[0]  = 0.0f;
        s[1]  = w.x;         s[2]  = w.y;         s[3]  = w.x + w.y;
        s[4]  = w.z;         s[5]  = w.x + w.z;   s[6]  = w.y + w.z;
        s[7]  = s[3] + w.z;  s[8]  = w.w;         s[9]  = w.x + w.w;
        s[10] = w.y + w.w;   s[11] = s[3] + w.w;  s[12] = w.z + w.w;
        s[13] = s[5] + w.w;  s[14] = s[6] + w.w;  s[15] = s[7] + w.w;
#pragma unroll
        for (int nb = 0; nb < 16; ++nb) lut[mat][g][nb][jj] = s[nb] + bias;
    }
    __syncthreads();

    // ---- uniform scalars
    float al[4], be[4], th[4];
#pragma unroll
    for (int i = 0; i < 4; ++i) {
        al[i] = fminf(fmaxf(alphas[i], 0.0f), 1.0f);
        be[i] = fminf(fmaxf(betas[i],  0.0f), 1.0f);
        th[i] = thrs[i];
    }
    const float pa = prelu_a[0];

    // ---- DPP row_ror direction probe: absorb direction into weight order
    const int pr = __builtin_amdgcn_update_dpp(0, lane, 0x121, 0xF, 0xF, true);
    const int d  = (__builtin_amdgcn_readfirstlane(pr) == 1) ? 1 : 15;

    // ---- MLP weights, bf16-packed in rotation order (shared by both rows)
    const int lx = l ^ 16;
    unsigned u1_oa[8], u1_ob[8], u1_xa[8], u1_xb[8];
    unsigned u2_o0[8], u2_o1[8], u2_x0[8], u2_x1[8];
#pragma unroll
    for (int q = 0; q < 8; ++q) {
        const int s0 = 2 * q, s1 = 2 * q + 1;
        const int i0 = ((l16 + d * s0) & 15) | gbase;
        const int i1 = ((l16 + d * s1) & 15) | gbase;
        u1_oa[q] = pack_bf16(W1[l         * kF + i0], W1[l         * kF + i1]);
        u1_ob[q] = pack_bf16(W1[(l + 32)  * kF + i0], W1[(l + 32)  * kF + i1]);
        u1_xa[q] = pack_bf16(W1[lx        * kF + i0], W1[lx        * kF + i1]);
        u1_xb[q] = pack_bf16(W1[(lx + 32) * kF + i0], W1[(lx + 32) * kF + i1]);
        u2_o0[q] = pack_bf16(W2[l  * 64 + i0],      W2[l  * 64 + i1]);
        u2_o1[q] = pack_bf16(W2[l  * 64 + i0 + 32], W2[l  * 64 + i1 + 32]);
        u2_x0[q] = pack_bf16(W2[lx * 64 + i0],      W2[lx * 64 + i1]);
        u2_x1[q] = pack_bf16(W2[lx * 64 + i0 + 32], W2[lx * 64 + i1 + 32]);
    }
    const float b1a = b1[l];
    const float b1b = b1[l + 32];
    const float ob  = b2[l];

    float synA[4] = {0.f, 0.f, 0.f, 0.f};
    float memA[4] = {0.f, 0.f, 0.f, 0.f};
    float synB[4] = {0.f, 0.f, 0.f, 0.f};
    float memB[4] = {0.f, 0.f, 0.f, 0.f};

    const float* xpA = x   + (bA * kT * kN + nA) * kF + l;
    float*       opA = out + (bA * kT * kN + nA) * kF + l;
    const float* xpB = x   + (bB * kT * kN + nB) * kF + l;
    float*       opB = out + (bB * kT * kN + nB) * kF + l;

    float xvA = xpA[0];
    float xvB = xpB[0];

    for (int t = 0; t < kT; ++t) {
        float xnA = 0.0f, xnB = 0.0f;
        if (t + 1 < kT) { xnA = xpA[(t + 1) * kNF]; xnB = xpB[(t + 1) * kNF]; }

        float hA = xvA, hB = xvB;
        float trA = 0.0f, trB = 0.0f;

#pragma unroll
        for (int i = 0; i < 4; ++i) {
            // synaptic_step for both rows (reset from PREVIOUS mem, detached)
            const float rstA = ((memA[i] - th[i]) > 0.0f) ? 1.0f : 0.0f;
            const float rstB = ((memB[i] - th[i]) > 0.0f) ? 1.0f : 0.0f;
            synA[i] = al[i] * synA[i] + hA;
            synB[i] = al[i] * synB[i] + hB;
            memA[i] = be[i] * memA[i] + synA[i] - rstA * th[i];
            memB[i] = be[i] * memB[i] + synB[i] - rstB * th[i];
            const bool spA = (memA[i] - th[i]) > 0.0f;
            const bool spB = (memB[i] - th[i]) > 0.0f;

            const unsigned long long a64 = __ballot(spA);
            const unsigned long long b64 = __ballot(spB);
            const unsigned mA = half ? (unsigned)(a64 >> 32) : (unsigned)a64;
            const unsigned mB = half ? (unsigned)(b64 >> 32) : (unsigned)b64;

            // binary matmul via nibble LUT (bias folded into g=0)
            float vA[8], vB[8];
#pragma unroll
            for (int g = 0; g < 8; ++g) {
                vA[g] = lut[i][g][(mA >> (4 * g)) & 15u][l];
                vB[g] = lut[i][g][(mB >> (4 * g)) & 15u][l];
            }
            const float accA = ((vA[0] + vA[1]) + (vA[2] + vA[3]))
                             + ((vA[4] + vA[5]) + (vA[6] + vA[7]));
            const float accB = ((vB[0] + vB[1]) + (vB[2] + vB[3]))
                             + ((vB[4] + vB[5]) + (vB[6] + vB[7]));
            if (i < 3) { hA = accA; hB = accB; }
            else       { trA = accA; trB = accB; }
        }

        // ---- MLP1: 32 -> 64 via DPP systolic, both rows share weight unpacks
        float oaA = b1a, obA = b1b, xaA = 0.0f, xbA = 0.0f;
        float oaB = b1a, obB = b1b, xaB = 0.0f, xbB = 0.0f;
        mlp1_steps2<0>(trA, trB, u1_oa, u1_ob, u1_xa, u1_xb,
                       oaA, obA, xaA, xbA, oaB, obB, xaB, xbB);
        const float h1aA = oaA + swz_x16(xaA);
        const float h1bA = obA + swz_x16(xbA);
        const float h1aB = oaB + swz_x16(xaB);
        const float h1bB = obB + swz_x16(xbB);
        const float g1A = (h1aA > 0.0f) ? h1aA : pa * h1aA;
        const float g2A = (h1bA > 0.0f) ? h1bA : pa * h1bA;
        const float g1B = (h1aB > 0.0f) ? h1aB : pa * h1aB;
        const float g2B = (h1bB > 0.0f) ? h1bB : pa * h1bB;

        // ---- MLP2: 64 -> 32 via DPP systolic
        float ooA = ob, xxA = 0.0f;
        float ooB = ob, xxB = 0.0f;
        mlp2_steps2<0>(g1A, g2A, g1B, g2B, u2_o0, u2_o1, u2_x0, u2_x1,
                       ooA, xxA, ooB, xxB);
        opA[t * kNF] = ooA + swz_x16(xxA);
        opB[t * kNF] = ooB + swz_x16(xxB);

        xvA = xnA;
        xvB = xnB;
    }
}
} // namespace

extern "C" void kernel_launch(void* const* d_in, const int* in_sizes, int n_in,
                              void* d_out, int out_size, void* d_ws, size_t ws_size,
                              hipStream_t stream) {
    const float* x        = (const float*)d_in[0];
    const float* alphas   = (const float*)d_in[1];
    const float* betas    = (const float*)d_in[2];
    const float* thrs     = (const float*)d_in[3];
    const float* chain_W  = (const float*)d_in[4];
    const float* chain_b  = (const float*)d_in[5];
    const float* lin_W    = (const float*)d_in[6];
    const float* lin_b    = (const float*)d_in[7];
    const float* W1       = (const float*)d_in[8];
    const float* b1       = (const float*)d_in[9];
    const float* prelu_a  = (const float*)d_in[10];
    const float* W2       = (const float*)d_in[11];
    const float* b2       = (const float*)d_in[12];
    float* out            = (float*)d_out;

    const int rows   = kB * kN;          // 16384
    const int blocks = rows / 32;        // 512 blocks * 8 waves * 4 rows/wave
    hipLaunchKernelGGL(snn_fused, dim3(blocks), dim3(512), 0, stream,
                       x, alphas, betas, thrs, chain_W, chain_b, lin_W, lin_b,
                       W1, b1, prelu_a, W2, b2, out);
}